// Round 2
// baseline (521.481 us; speedup 1.0000x reference)
//
#include <hip/hip_runtime.h>
#include <hip/hip_bf16.h>

// OLMoE sparse MoE block. ALL tensors fp32 in memory (per reference);
// compute uses bf16 MFMA (tolerance floor_eps_k=8 permits bf16 compute).
// T=1024 tokens, H=2048, I=1024, E=8, top-2, unweighted combine.
// d_in: x[1024,2048], gate_w[8,2048], w_gate[8,2048,1024], w_up[8,2048,1024], w_down[8,1024,2048]
// d_out: out[1024,2048] fp32, then router_logits[1024,8] fp32

#define NT 1024
#define HD 2048
#define ID 1024
#define NE 8

typedef __bf16 v8bf __attribute__((ext_vector_type(8)));
typedef float v4f __attribute__((ext_vector_type(4)));

#define BM 64
#define BN 64
#define BK 32
#define LDP 40  // padded LDS row length (elements); 80B rows keep 16B alignment

__device__ __forceinline__ v8bf cvt8(float4 a, float4 b) {
    v8bf v;
    v[0] = (__bf16)a.x; v[1] = (__bf16)a.y; v[2] = (__bf16)a.z; v[3] = (__bf16)a.w;
    v[4] = (__bf16)b.x; v[5] = (__bf16)b.y; v[6] = (__bf16)b.z; v[7] = (__bf16)b.w;
    return v;
}

// ---------------- router (fp32 exact) ----------------
__global__ __launch_bounds__(256) void router_kernel(
    const float* __restrict__ x, const float* __restrict__ gw,
    float* __restrict__ logits_out, int* __restrict__ topids, int* __restrict__ counts)
{
    int t = blockIdx.x;
    int tid = threadIdx.x;
    __shared__ float sm[256][NE];

    const float* xr = x + (size_t)t * HD + tid * 8;
    float4 x0 = *(const float4*)xr;
    float4 x1 = *(const float4*)(xr + 4);
    float xf[8] = {x0.x, x0.y, x0.z, x0.w, x1.x, x1.y, x1.z, x1.w};

#pragma unroll
    for (int e = 0; e < NE; e++) {
        const float* wr = gw + (size_t)e * HD + tid * 8;
        float4 w0 = *(const float4*)wr;
        float4 w1 = *(const float4*)(wr + 4);
        float s = xf[0]*w0.x + xf[1]*w0.y + xf[2]*w0.z + xf[3]*w0.w
                + xf[4]*w1.x + xf[5]*w1.y + xf[6]*w1.z + xf[7]*w1.w;
        sm[tid][e] = s;
    }
    __syncthreads();
    if (tid < NE) {
        float s = 0.f;
        for (int i = 0; i < 256; i++) s += sm[i][tid];
        sm[0][tid] = s;
    }
    __syncthreads();
    if (tid == 0) {
        float lg[NE];
#pragma unroll
        for (int e = 0; e < NE; e++) {
            lg[e] = sm[0][e];
            logits_out[t * NE + e] = lg[e];
        }
        int i1 = 0;
        for (int e = 1; e < NE; e++) if (lg[e] > lg[i1]) i1 = e;
        int i2 = -1;
        for (int e = 0; e < NE; e++) {
            if (e == i1) continue;
            if (i2 < 0 || lg[e] > lg[i2]) i2 = e;
        }
        topids[t * 2 + 0] = i1;
        topids[t * 2 + 1] = i2;
        atomicAdd(&counts[i1], 1);
        atomicAdd(&counts[i2], 1);
    }
}

// ---------------- scan ----------------
__global__ void scan_kernel(const int* __restrict__ counts, int* __restrict__ base, int* __restrict__ cursor)
{
    if (threadIdx.x == 0 && blockIdx.x == 0) {
        int s = 0;
        for (int e = 0; e < NE; e++) { base[e] = s; cursor[e] = s; s += counts[e]; }
    }
}

// ---------------- assign ----------------
__global__ void assign_kernel(const int* __restrict__ topids, int* __restrict__ cursor,
                              int* __restrict__ rowtok, int* __restrict__ toppos)
{
    int t = blockIdx.x * blockDim.x + threadIdx.x;
    if (t < NT) {
#pragma unroll
        for (int s = 0; s < 2; s++) {
            int e = topids[t * 2 + s];
            int pos = atomicAdd(&cursor[e], 1);
            rowtok[pos] = t;
            toppos[t * 2 + s] = pos;
        }
    }
}

// ---------------- GEMM1: h = silu(X Wg) * (X Wu), fp32 in, bf16 out ----------------
__global__ __launch_bounds__(256) void gemm1_kernel(
    const float* __restrict__ x, const float* __restrict__ wg, const float* __restrict__ wu,
    const int* __restrict__ counts, const int* __restrict__ basev, const int* __restrict__ rowtok,
    __bf16* __restrict__ hbuf)
{
    int e = blockIdx.z;
    int cnt = counts[e];
    int tile_m = blockIdx.y;
    if (tile_m * BM >= cnt) return;
    int n0 = blockIdx.x * BN;
    int base = basev[e];

    __shared__ __align__(16) __bf16 Ald[BM][LDP];
    __shared__ __align__(16) __bf16 BgT[BN][LDP];
    __shared__ __align__(16) __bf16 BuT[BN][LDP];

    int tid = threadIdx.x;
    int lane = tid & 63;
    int w = tid >> 6;
    int q = lane >> 4;
    int ml = lane & 15;

    v4f accg[4], accu[4];
#pragma unroll
    for (int c = 0; c < 4; c++) { accg[c] = (v4f){0,0,0,0}; accu[c] = (v4f){0,0,0,0}; }

    // A staging: 4 threads per row, 8 floats each
    int ar = tid >> 2;
    int aseg = tid & 3;
    int grow = tile_m * BM + ar;
    const float* arow = nullptr;
    if (grow < cnt) arow = x + (size_t)rowtok[base + grow] * HD;

    // B staging: 8 floats/thread/matrix, transposed scatter into LDS
    int bkk = tid >> 3;          // k within tile: 0..31
    int bnb = (tid & 7) * 8;     // n within tile: 0..56
    const float* wge = wg + (size_t)e * HD * ID;
    const float* wue = wu + (size_t)e * HD * ID;

    for (int k0 = 0; k0 < HD; k0 += BK) {
        __syncthreads();
        float4 a0 = {0,0,0,0}, a1 = {0,0,0,0};
        if (arow) {
            a0 = *(const float4*)(arow + k0 + aseg * 8);
            a1 = *(const float4*)(arow + k0 + aseg * 8 + 4);
        }
        *(v8bf*)&Ald[ar][aseg * 8] = cvt8(a0, a1);

        const float* bgp = wge + (size_t)(k0 + bkk) * ID + n0 + bnb;
        float4 g0 = *(const float4*)bgp;
        float4 g1 = *(const float4*)(bgp + 4);
        const float* bup = wue + (size_t)(k0 + bkk) * ID + n0 + bnb;
        float4 u0 = *(const float4*)bup;
        float4 u1 = *(const float4*)(bup + 4);
        v8bf gv = cvt8(g0, g1), uv = cvt8(u0, u1);
#pragma unroll
        for (int j = 0; j < 8; j++) { BgT[bnb + j][bkk] = gv[j]; BuT[bnb + j][bkk] = uv[j]; }
        __syncthreads();

        v8bf af = *(const v8bf*)&Ald[w * 16 + ml][q * 8];
#pragma unroll
        for (int c = 0; c < 4; c++) {
            v8bf bgf = *(const v8bf*)&BgT[c * 16 + ml][q * 8];
            accg[c] = __builtin_amdgcn_mfma_f32_16x16x32_bf16(af, bgf, accg[c], 0, 0, 0);
            v8bf buf = *(const v8bf*)&BuT[c * 16 + ml][q * 8];
            accu[c] = __builtin_amdgcn_mfma_f32_16x16x32_bf16(af, buf, accu[c], 0, 0, 0);
        }
    }

#pragma unroll
    for (int c = 0; c < 4; c++) {
#pragma unroll
        for (int r = 0; r < 4; r++) {
            int row = tile_m * BM + w * 16 + q * 4 + r;
            if (row < cnt) {
                float g = accg[c][r];
                float u = accu[c][r];
                float hv = g / (1.f + __expf(-g)) * u;
                hbuf[(size_t)(base + row) * ID + n0 + c * 16 + ml] = (__bf16)hv;
            }
        }
    }
}

// ---------------- GEMM2: y = h Wd, bf16 A, fp32 B -> bf16 out ----------------
__global__ __launch_bounds__(256) void gemm2_kernel(
    const __bf16* __restrict__ hbuf, const float* __restrict__ wd,
    const int* __restrict__ counts, const int* __restrict__ basev,
    __bf16* __restrict__ ybuf)
{
    int e = blockIdx.z;
    int cnt = counts[e];
    int tile_m = blockIdx.y;
    if (tile_m * BM >= cnt) return;
    int n0 = blockIdx.x * BN;
    int base = basev[e];

    __shared__ __align__(16) __bf16 Ald[BM][LDP];
    __shared__ __align__(16) __bf16 BdT[BN][LDP];

    int tid = threadIdx.x;
    int lane = tid & 63;
    int w = tid >> 6;
    int q = lane >> 4;
    int ml = lane & 15;

    v4f acc[4];
#pragma unroll
    for (int c = 0; c < 4; c++) acc[c] = (v4f){0,0,0,0};

    int ar = tid >> 2;
    int aseg = tid & 3;
    int grow = tile_m * BM + ar;
    const __bf16* arow = nullptr;
    if (grow < cnt) arow = hbuf + (size_t)(base + grow) * ID;

    int bkk = tid >> 3;
    int bnb = (tid & 7) * 8;
    const float* wde = wd + (size_t)e * ID * HD;

    for (int k0 = 0; k0 < ID; k0 += BK) {
        __syncthreads();
        v8bf av;
#pragma unroll
        for (int j = 0; j < 8; j++) av[j] = (__bf16)0.f;
        if (arow) av = *(const v8bf*)(arow + k0 + aseg * 8);
        *(v8bf*)&Ald[ar][aseg * 8] = av;

        const float* bdp = wde + (size_t)(k0 + bkk) * HD + n0 + bnb;
        float4 d0 = *(const float4*)bdp;
        float4 d1 = *(const float4*)(bdp + 4);
        v8bf dv = cvt8(d0, d1);
#pragma unroll
        for (int j = 0; j < 8; j++) BdT[bnb + j][bkk] = dv[j];
        __syncthreads();

        v8bf af = *(const v8bf*)&Ald[w * 16 + ml][q * 8];
#pragma unroll
        for (int c = 0; c < 4; c++) {
            v8bf bdf = *(const v8bf*)&BdT[c * 16 + ml][q * 8];
            acc[c] = __builtin_amdgcn_mfma_f32_16x16x32_bf16(af, bdf, acc[c], 0, 0, 0);
        }
    }

#pragma unroll
    for (int c = 0; c < 4; c++) {
#pragma unroll
        for (int r = 0; r < 4; r++) {
            int row = tile_m * BM + w * 16 + q * 4 + r;
            if (row < cnt) {
                ybuf[(size_t)(base + row) * HD + n0 + c * 16 + ml] = (__bf16)acc[c][r];
            }
        }
    }
}

// ---------------- combine: out[t] = y[p0] + y[p1], fp32 out ----------------
__global__ __launch_bounds__(256) void combine_kernel(
    const __bf16* __restrict__ ybuf, const int* __restrict__ toppos, float* __restrict__ out)
{
    int t = blockIdx.x;
    int tid = threadIdx.x;
    int p0 = toppos[t * 2 + 0];
    int p1 = toppos[t * 2 + 1];
    v8bf a = ((const v8bf*)(ybuf + (size_t)p0 * HD))[tid];
    v8bf b = ((const v8bf*)(ybuf + (size_t)p1 * HD))[tid];
    float4 o0, o1;
    o0.x = (float)a[0] + (float)b[0];
    o0.y = (float)a[1] + (float)b[1];
    o0.z = (float)a[2] + (float)b[2];
    o0.w = (float)a[3] + (float)b[3];
    o1.x = (float)a[4] + (float)b[4];
    o1.y = (float)a[5] + (float)b[5];
    o1.z = (float)a[6] + (float)b[6];
    o1.w = (float)a[7] + (float)b[7];
    float* orow = out + (size_t)t * HD + tid * 8;
    *(float4*)orow = o0;
    *(float4*)(orow + 4) = o1;
}

extern "C" void kernel_launch(void* const* d_in, const int* in_sizes, int n_in,
                              void* d_out, int out_size, void* d_ws, size_t ws_size,
                              hipStream_t stream)
{
    const float* x  = (const float*)d_in[0];
    const float* gw = (const float*)d_in[1];
    const float* wg = (const float*)d_in[2];
    const float* wu = (const float*)d_in[3];
    const float* wd = (const float*)d_in[4];
    float* out = (float*)d_out;
    float* logits = out + (size_t)NT * HD;

    char* ws = (char*)d_ws;
    int* counts = (int*)(ws + 0);
    int* base   = (int*)(ws + 64);
    int* cursor = (int*)(ws + 128);
    int* topids = (int*)(ws + 1024);                 // 2048 ints
    int* toppos = (int*)(ws + 1024 + 8192);          // 2048 ints
    int* rowtok = (int*)(ws + 1024 + 16384);         // 2048 ints
    __bf16* hbuf = (__bf16*)(ws + 32768);                          // [2048,1024] bf16 = 4 MB
    __bf16* ybuf = (__bf16*)(ws + 32768 + (size_t)2048 * ID * 2);  // [2048,2048] bf16 = 8 MB

    hipMemsetAsync(ws, 0, 256, stream);
    router_kernel<<<NT, 256, 0, stream>>>(x, gw, logits, topids, counts);
    scan_kernel<<<1, 64, 0, stream>>>(counts, base, cursor);
    assign_kernel<<<4, 256, 0, stream>>>(topids, cursor, rowtok, toppos);
    gemm1_kernel<<<dim3(ID / BN, NT / BM, NE), 256, 0, stream>>>(x, wg, wu, counts, base, rowtok, hbuf);
    gemm2_kernel<<<dim3(HD / BN, NT / BM, NE), 256, 0, stream>>>(hbuf, wd, counts, base, ybuf);
    combine_kernel<<<NT, 256, 0, stream>>>(ybuf, toppos, out);
}

// Round 3
// 418.471 us; speedup vs baseline: 1.2462x; 1.2462x over previous
//
#include <hip/hip_runtime.h>
#include <hip/hip_bf16.h>
#include <math.h>

// OLMoE sparse MoE block. fp32 storage, bf16 MFMA compute (32x32x16).
// T=1024, H=2048, I=1024, E=8, top-2, unweighted combine.

#define NT 1024
#define HD 2048
#define ID 1024
#define NE 8
#define LDP 40  // LDS row pitch (bf16 elements): 80B rows, 16B-aligned frags

typedef __bf16 v8bf __attribute__((ext_vector_type(8)));
typedef __bf16 v2bf __attribute__((ext_vector_type(2)));
typedef float v16f __attribute__((ext_vector_type(16)));

__device__ __forceinline__ v8bf cvt8(float4 a, float4 b) {
    v8bf v;
    v[0] = (__bf16)a.x; v[1] = (__bf16)a.y; v[2] = (__bf16)a.z; v[3] = (__bf16)a.w;
    v[4] = (__bf16)b.x; v[5] = (__bf16)b.y; v[6] = (__bf16)b.z; v[7] = (__bf16)b.w;
    return v;
}

// ---------------- router: one wave per token ----------------
__global__ __launch_bounds__(256) void router_kernel(
    const float* __restrict__ x, const float* __restrict__ gw,
    float* __restrict__ logits_out, int* __restrict__ topids, int* __restrict__ counts)
{
    int wv = threadIdx.x >> 6, ln = threadIdx.x & 63;
    int t = blockIdx.x * 4 + wv;
    const float* xr = x + (size_t)t * HD + ln * 32;
    float4 xv[8];
#pragma unroll
    for (int i = 0; i < 8; i++) xv[i] = *(const float4*)(xr + i * 4);

    float lg[NE];
#pragma unroll
    for (int e = 0; e < NE; e++) {
        const float* wr = gw + (size_t)e * HD + ln * 32;
        float s = 0.f;
#pragma unroll
        for (int i = 0; i < 8; i++) {
            float4 w4 = *(const float4*)(wr + i * 4);
            s += xv[i].x * w4.x + xv[i].y * w4.y + xv[i].z * w4.z + xv[i].w * w4.w;
        }
#pragma unroll
        for (int off = 32; off > 0; off >>= 1) s += __shfl_down(s, off, 64);
        lg[e] = s;  // valid on lane 0
    }
    if (ln == 0) {
#pragma unroll
        for (int e = 0; e < NE; e++) logits_out[t * NE + e] = lg[e];
        int i1 = 0;
        for (int e = 1; e < NE; e++) if (lg[e] > lg[i1]) i1 = e;
        int i2 = -1;
        for (int e = 0; e < NE; e++) {
            if (e == i1) continue;
            if (i2 < 0 || lg[e] > lg[i2]) i2 = e;
        }
        topids[t * 2 + 0] = i1;
        topids[t * 2 + 1] = i2;
        atomicAdd(&counts[i1], 1);
        atomicAdd(&counts[i2], 1);
    }
}

__global__ void scan_kernel(const int* __restrict__ counts, int* __restrict__ base, int* __restrict__ cursor)
{
    if (threadIdx.x == 0 && blockIdx.x == 0) {
        int s = 0;
        for (int e = 0; e < NE; e++) { base[e] = s; cursor[e] = s; s += counts[e]; }
    }
}

__global__ void assign_kernel(const int* __restrict__ topids, int* __restrict__ cursor,
                              int* __restrict__ rowtok, int* __restrict__ toppos)
{
    int t = blockIdx.x * blockDim.x + threadIdx.x;
    if (t < NT) {
#pragma unroll
        for (int s = 0; s < 2; s++) {
            int e = topids[t * 2 + s];
            int pos = atomicAdd(&cursor[e], 1);
            rowtok[pos] = t;
            toppos[t * 2 + s] = pos;
        }
    }
}

// ---------------- GEMM1: h = silu(X Wg) * (X Wu) ----------------
// block tile: M128 x N64 (same 64 cols of gate AND up). 256 thr = 4 waves.
// wave tile: 64M x 32N for both matrices, as 2x1 32x32 MFMA tiles x2 mats.
__global__ __launch_bounds__(256) void gemm1_kernel(
    const float* __restrict__ x, const float* __restrict__ wg, const float* __restrict__ wu,
    const int* __restrict__ counts, const int* __restrict__ basev, const int* __restrict__ rowtok,
    __bf16* __restrict__ hbuf)
{
    int e = blockIdx.z;
    int cnt = counts[e];
    int m0 = blockIdx.y * 128;
    if (m0 >= cnt) return;
    int n0 = blockIdx.x * 64;
    int base = basev[e];

    __shared__ __align__(16) __bf16 Ald[128][LDP];
    __shared__ __align__(16) __bf16 Bg[64][LDP];
    __shared__ __align__(16) __bf16 Bu[64][LDP];

    int tid = threadIdx.x;
    int w = tid >> 6, ln = tid & 63, ml = ln & 31, hh = ln >> 5;
    int wm = (w & 1) * 64;       // wave m-base within block
    int wn = (w >> 1) * 32;      // wave n-base within block

    // A staging: thread -> row am (0..127), k-half aseg
    int am = tid >> 1, aseg = tid & 1;
    const float* arow = nullptr;
    if (m0 + am < cnt) arow = x + (size_t)rowtok[base + m0 + am] * HD;

    // B staging: kp = 2*(tid&15) (even k), bn = 4*(tid>>4); conflict-free pair writes
    int kp = (tid & 15) * 2;
    int bn = (tid >> 4) * 4;
    const float* wge = wg + (size_t)e * HD * ID + n0 + bn;
    const float* wue = wu + (size_t)e * HD * ID + n0 + bn;

    v16f accg[2], accu[2];
#pragma unroll
    for (int mt = 0; mt < 2; mt++) {
#pragma unroll
        for (int r = 0; r < 16; r++) { accg[mt][r] = 0.f; accu[mt][r] = 0.f; }
    }

    for (int k0 = 0; k0 < HD; k0 += 32) {
        __syncthreads();
        // stage A (fp32 -> bf16), 2 x ds_write_b128
        float4 a0 = {0,0,0,0}, a1 = {0,0,0,0}, a2 = {0,0,0,0}, a3 = {0,0,0,0};
        if (arow) {
            const float* ap = arow + k0 + aseg * 16;
            a0 = *(const float4*)(ap);
            a1 = *(const float4*)(ap + 4);
            a2 = *(const float4*)(ap + 8);
            a3 = *(const float4*)(ap + 12);
        }
        *(v8bf*)&Ald[am][aseg * 16]     = cvt8(a0, a1);
        *(v8bf*)&Ald[am][aseg * 16 + 8] = cvt8(a2, a3);

        // stage B transposed: rows k0+kp, k0+kp+1; write (k,k+1) bf16 pairs
        {
            const float* p0 = wge + (size_t)(k0 + kp) * ID;
            float4 g0 = *(const float4*)p0;
            float4 g1 = *(const float4*)(p0 + ID);
            const float* p1 = wue + (size_t)(k0 + kp) * ID;
            float4 u0 = *(const float4*)p1;
            float4 u1 = *(const float4*)(p1 + ID);
            float g0a[4] = {g0.x, g0.y, g0.z, g0.w}, g1a[4] = {g1.x, g1.y, g1.z, g1.w};
            float u0a[4] = {u0.x, u0.y, u0.z, u0.w}, u1a[4] = {u1.x, u1.y, u1.z, u1.w};
#pragma unroll
            for (int j = 0; j < 4; j++) {
                v2bf pg; pg[0] = (__bf16)g0a[j]; pg[1] = (__bf16)g1a[j];
                *(v2bf*)&Bg[bn + j][kp] = pg;
                v2bf pu; pu[0] = (__bf16)u0a[j]; pu[1] = (__bf16)u1a[j];
                *(v2bf*)&Bu[bn + j][kp] = pu;
            }
        }
        __syncthreads();

#pragma unroll
        for (int kh = 0; kh < 2; kh++) {
            int kb = kh * 16 + hh * 8;
            v8bf af0 = *(const v8bf*)&Ald[wm + ml][kb];
            v8bf af1 = *(const v8bf*)&Ald[wm + 32 + ml][kb];
            v8bf bg  = *(const v8bf*)&Bg[wn + ml][kb];
            v8bf bu  = *(const v8bf*)&Bu[wn + ml][kb];
            accg[0] = __builtin_amdgcn_mfma_f32_32x32x16_bf16(af0, bg, accg[0], 0, 0, 0);
            accg[1] = __builtin_amdgcn_mfma_f32_32x32x16_bf16(af1, bg, accg[1], 0, 0, 0);
            accu[0] = __builtin_amdgcn_mfma_f32_32x32x16_bf16(af0, bu, accu[0], 0, 0, 0);
            accu[1] = __builtin_amdgcn_mfma_f32_32x32x16_bf16(af1, bu, accu[1], 0, 0, 0);
        }
    }

    // epilogue: h = silu(g)*u, bf16 store
#pragma unroll
    for (int mt = 0; mt < 2; mt++) {
#pragma unroll
        for (int r = 0; r < 16; r++) {
            int row = wm + mt * 32 + (r & 3) + 8 * (r >> 2) + 4 * hh;
            if (m0 + row < cnt) {
                float g = accg[mt][r];
                float u = accu[mt][r];
                float hv = g / (1.f + __expf(-g)) * u;
                hbuf[(size_t)(base + m0 + row) * ID + n0 + wn + ml] = (__bf16)hv;
            }
        }
    }
}

// ---------------- GEMM2: y = h Wd ----------------
// block tile: M128 x N128. wave tile 64x64 = 2x2 32x32 tiles.
__global__ __launch_bounds__(256) void gemm2_kernel(
    const __bf16* __restrict__ hbuf, const float* __restrict__ wd,
    const int* __restrict__ counts, const int* __restrict__ basev,
    __bf16* __restrict__ ybuf)
{
    int e = blockIdx.z;
    int cnt = counts[e];
    int m0 = blockIdx.y * 128;
    if (m0 >= cnt) return;
    int n0 = blockIdx.x * 128;
    int base = basev[e];

    __shared__ __align__(16) __bf16 Ald[128][LDP];
    __shared__ __align__(16) __bf16 Bd[128][LDP];

    int tid = threadIdx.x;
    int w = tid >> 6, ln = tid & 63, ml = ln & 31, hh = ln >> 5;
    int wm = (w & 1) * 64;
    int wn = (w >> 1) * 64;

    // A staging: bf16 rows, no conversion
    int am = tid >> 1, aseg = tid & 1;
    int grow = m0 + am;
    int arow = base + (grow < cnt ? grow : (cnt - 1));  // clamp; masked at store
    const __bf16* ap0 = hbuf + (size_t)arow * ID;

    // B staging: kp even k, bn quad; two n-passes for 128 cols
    int kp = (tid & 15) * 2;
    int bnq = (tid >> 4) * 4;
    const float* wde = wd + (size_t)e * ID * HD + n0;

    v16f acc[2][2];
#pragma unroll
    for (int mt = 0; mt < 2; mt++)
#pragma unroll
        for (int nt = 0; nt < 2; nt++)
#pragma unroll
            for (int r = 0; r < 16; r++) acc[mt][nt][r] = 0.f;

    for (int k0 = 0; k0 < ID; k0 += 32) {
        __syncthreads();
        // stage A: 2 x v8bf direct
        *(v8bf*)&Ald[am][aseg * 16]     = *(const v8bf*)(ap0 + k0 + aseg * 16);
        *(v8bf*)&Ald[am][aseg * 16 + 8] = *(const v8bf*)(ap0 + k0 + aseg * 16 + 8);

        // stage B transposed, 128 cols in two passes
#pragma unroll
        for (int rr = 0; rr < 2; rr++) {
            int bn = bnq + rr * 64;
            const float* p0 = wde + (size_t)(k0 + kp) * HD + bn;
            float4 d0 = *(const float4*)p0;
            float4 d1 = *(const float4*)(p0 + HD);
            float d0a[4] = {d0.x, d0.y, d0.z, d0.w}, d1a[4] = {d1.x, d1.y, d1.z, d1.w};
#pragma unroll
            for (int j = 0; j < 4; j++) {
                v2bf pd; pd[0] = (__bf16)d0a[j]; pd[1] = (__bf16)d1a[j];
                *(v2bf*)&Bd[bn + j][kp] = pd;
            }
        }
        __syncthreads();

#pragma unroll
        for (int kh = 0; kh < 2; kh++) {
            int kb = kh * 16 + hh * 8;
            v8bf af0 = *(const v8bf*)&Ald[wm + ml][kb];
            v8bf af1 = *(const v8bf*)&Ald[wm + 32 + ml][kb];
            v8bf bf0 = *(const v8bf*)&Bd[wn + ml][kb];
            v8bf bf1 = *(const v8bf*)&Bd[wn + 32 + ml][kb];
            acc[0][0] = __builtin_amdgcn_mfma_f32_32x32x16_bf16(af0, bf0, acc[0][0], 0, 0, 0);
            acc[1][0] = __builtin_amdgcn_mfma_f32_32x32x16_bf16(af1, bf0, acc[1][0], 0, 0, 0);
            acc[0][1] = __builtin_amdgcn_mfma_f32_32x32x16_bf16(af0, bf1, acc[0][1], 0, 0, 0);
            acc[1][1] = __builtin_amdgcn_mfma_f32_32x32x16_bf16(af1, bf1, acc[1][1], 0, 0, 0);
        }
    }

#pragma unroll
    for (int mt = 0; mt < 2; mt++) {
#pragma unroll
        for (int nt = 0; nt < 2; nt++) {
#pragma unroll
            for (int r = 0; r < 16; r++) {
                int row = wm + mt * 32 + (r & 3) + 8 * (r >> 2) + 4 * hh;
                if (m0 + row < cnt) {
                    ybuf[(size_t)(base + m0 + row) * HD + n0 + wn + nt * 32 + ml] = (__bf16)acc[mt][nt][r];
                }
            }
        }
    }
}

// ---------------- combine ----------------
__global__ __launch_bounds__(256) void combine_kernel(
    const __bf16* __restrict__ ybuf, const int* __restrict__ toppos, float* __restrict__ out)
{
    int t = blockIdx.x;
    int tid = threadIdx.x;
    int p0 = toppos[t * 2 + 0];
    int p1 = toppos[t * 2 + 1];
    v8bf a = ((const v8bf*)(ybuf + (size_t)p0 * HD))[tid];
    v8bf b = ((const v8bf*)(ybuf + (size_t)p1 * HD))[tid];
    float4 o0, o1;
    o0.x = (float)a[0] + (float)b[0];
    o0.y = (float)a[1] + (float)b[1];
    o0.z = (float)a[2] + (float)b[2];
    o0.w = (float)a[3] + (float)b[3];
    o1.x = (float)a[4] + (float)b[4];
    o1.y = (float)a[5] + (float)b[5];
    o1.z = (float)a[6] + (float)b[6];
    o1.w = (float)a[7] + (float)b[7];
    float* orow = out + (size_t)t * HD + tid * 8;
    *(float4*)orow = o0;
    *(float4*)(orow + 4) = o1;
}

extern "C" void kernel_launch(void* const* d_in, const int* in_sizes, int n_in,
                              void* d_out, int out_size, void* d_ws, size_t ws_size,
                              hipStream_t stream)
{
    const float* x  = (const float*)d_in[0];
    const float* gw = (const float*)d_in[1];
    const float* wg = (const float*)d_in[2];
    const float* wu = (const float*)d_in[3];
    const float* wd = (const float*)d_in[4];
    float* out = (float*)d_out;
    float* logits = out + (size_t)NT * HD;

    char* ws = (char*)d_ws;
    int* counts = (int*)(ws + 0);
    int* base   = (int*)(ws + 64);
    int* cursor = (int*)(ws + 128);
    int* topids = (int*)(ws + 1024);
    int* toppos = (int*)(ws + 1024 + 8192);
    int* rowtok = (int*)(ws + 1024 + 16384);
    __bf16* hbuf = (__bf16*)(ws + 32768);                          // [2048,1024] bf16 = 4 MB
    __bf16* ybuf = (__bf16*)(ws + 32768 + (size_t)2048 * ID * 2);  // [2048,2048] bf16 = 8 MB

    hipMemsetAsync(ws, 0, 256, stream);
    router_kernel<<<NT / 4, 256, 0, stream>>>(x, gw, logits, topids, counts);
    scan_kernel<<<1, 64, 0, stream>>>(counts, base, cursor);
    assign_kernel<<<4, 256, 0, stream>>>(topids, cursor, rowtok, toppos);
    gemm1_kernel<<<dim3(ID / 64, 16, NE), 256, 0, stream>>>(x, wg, wu, counts, base, rowtok, hbuf);
    gemm2_kernel<<<dim3(HD / 128, 16, NE), 256, 0, stream>>>(hbuf, wd, counts, base, ybuf);
    combine_kernel<<<NT, 256, 0, stream>>>(ybuf, toppos, out);
}

// Round 4
// 363.978 us; speedup vs baseline: 1.4327x; 1.1497x over previous
//
#include <hip/hip_runtime.h>
#include <hip/hip_bf16.h>
#include <math.h>

// OLMoE sparse MoE block. fp32 storage, bf16 MFMA compute (32x32x16).
// T=1024, H=2048, I=1024, E=8, top-2, unweighted combine.

#define NT 1024
#define HD 2048
#define ID 1024
#define NE 8
#define LDP 40  // LDS row pitch (bf16 elements): 80B rows, 16B-aligned octs

typedef __bf16 v8bf __attribute__((ext_vector_type(8)));
typedef __bf16 v2bf __attribute__((ext_vector_type(2)));
typedef float v16f __attribute__((ext_vector_type(16)));

__device__ __forceinline__ v8bf cvt8(float4 a, float4 b) {
    v8bf v;
    v[0] = (__bf16)a.x; v[1] = (__bf16)a.y; v[2] = (__bf16)a.z; v[3] = (__bf16)a.w;
    v[4] = (__bf16)b.x; v[5] = (__bf16)b.y; v[6] = (__bf16)b.z; v[7] = (__bf16)b.w;
    return v;
}

// ---------------- router: one wave per token ----------------
__global__ __launch_bounds__(256) void router_kernel(
    const float* __restrict__ x, const float* __restrict__ gw,
    float* __restrict__ logits_out, int* __restrict__ topids, int* __restrict__ counts)
{
    int wv = threadIdx.x >> 6, ln = threadIdx.x & 63;
    int t = blockIdx.x * 4 + wv;
    const float* xr = x + (size_t)t * HD + ln * 32;
    float4 xv[8];
#pragma unroll
    for (int i = 0; i < 8; i++) xv[i] = *(const float4*)(xr + i * 4);

    float lg[NE];
#pragma unroll
    for (int e = 0; e < NE; e++) {
        const float* wr = gw + (size_t)e * HD + ln * 32;
        float s = 0.f;
#pragma unroll
        for (int i = 0; i < 8; i++) {
            float4 w4 = *(const float4*)(wr + i * 4);
            s += xv[i].x * w4.x + xv[i].y * w4.y + xv[i].z * w4.z + xv[i].w * w4.w;
        }
#pragma unroll
        for (int off = 32; off > 0; off >>= 1) s += __shfl_down(s, off, 64);
        lg[e] = s;  // valid on lane 0
    }
    if (ln == 0) {
#pragma unroll
        for (int e = 0; e < NE; e++) logits_out[t * NE + e] = lg[e];
        int i1 = 0;
        for (int e = 1; e < NE; e++) if (lg[e] > lg[i1]) i1 = e;
        int i2 = -1;
        for (int e = 0; e < NE; e++) {
            if (e == i1) continue;
            if (i2 < 0 || lg[e] > lg[i2]) i2 = e;
        }
        topids[t * 2 + 0] = i1;
        topids[t * 2 + 1] = i2;
        atomicAdd(&counts[i1], 1);
        atomicAdd(&counts[i2], 1);
    }
}

__global__ void scan_kernel(const int* __restrict__ counts, int* __restrict__ base, int* __restrict__ cursor)
{
    if (threadIdx.x == 0 && blockIdx.x == 0) {
        int s = 0;
        for (int e = 0; e < NE; e++) { base[e] = s; cursor[e] = s; s += counts[e]; }
    }
}

__global__ void assign_kernel(const int* __restrict__ topids, int* __restrict__ cursor,
                              int* __restrict__ rowtok, int* __restrict__ toppos)
{
    int t = blockIdx.x * blockDim.x + threadIdx.x;
    if (t < NT) {
#pragma unroll
        for (int s = 0; s < 2; s++) {
            int e = topids[t * 2 + s];
            int pos = atomicAdd(&cursor[e], 1);
            rowtok[pos] = t;
            toppos[t * 2 + s] = pos;
        }
    }
}

// ---------------- GEMM1: h = silu(X Wg) * (X Wu) ----------------
// block tile M128 x N64, double-buffered LDS, register prefetch.
// B staging: coalesced loads (lanes->n), oct-XOR-swizzled LDS columns.
__global__ __launch_bounds__(256) void gemm1_kernel(
    const float* __restrict__ x, const float* __restrict__ wg, const float* __restrict__ wu,
    const int* __restrict__ counts, const int* __restrict__ basev, const int* __restrict__ rowtok,
    __bf16* __restrict__ hbuf)
{
    int e = blockIdx.z;
    int cnt = counts[e];
    int m0 = blockIdx.y * 128;
    if (m0 >= cnt) return;
    int n0 = blockIdx.x * 64;
    int base = basev[e];

    __shared__ __align__(16) __bf16 Ald[2][128][LDP];
    __shared__ __align__(16) __bf16 Bg[2][64][LDP];
    __shared__ __align__(16) __bf16 Bu[2][64][LDP];

    int tid = threadIdx.x;
    int w = tid >> 6, ln = tid & 63, ml = ln & 31, hh = ln >> 5;
    int wm = (w & 1) * 64, wn = (w >> 1) * 32;

    // A staging role: row am, k-half aseg (16 floats)
    int am = tid >> 1, aseg = tid & 1;
    const float* arow = nullptr;
    if (m0 + am < cnt) arow = x + (size_t)rowtok[base + m0 + am] * HD + aseg * 16;

    // B staging role: lanes contiguous in n (coalesced); pair rows kp,kp+1
    int s = tid & 15, P = tid >> 4;
    int bn = s * 4;
    int kp = P * 2;
    int bcol = 8 * ((P >> 2) ^ (s & 3)) + 2 * (P & 3);  // oct-XOR swizzle
    const float* wge = wg + (size_t)e * HD * ID + n0 + bn;
    const float* wue = wu + (size_t)e * HD * ID + n0 + bn;

    v16f accg[2], accu[2];
#pragma unroll
    for (int mt = 0; mt < 2; mt++)
#pragma unroll
        for (int r = 0; r < 16; r++) { accg[mt][r] = 0.f; accu[mt][r] = 0.f; }

    float4 a0, a1, a2, a3, g0, g1, u0, u1;

#define G1_LOAD(K0) do { \
        if (arow) { \
            a0 = *(const float4*)(arow + (K0)); \
            a1 = *(const float4*)(arow + (K0) + 4); \
            a2 = *(const float4*)(arow + (K0) + 8); \
            a3 = *(const float4*)(arow + (K0) + 12); \
        } else { a0 = a1 = a2 = a3 = (float4){0,0,0,0}; } \
        const float* pg_ = wge + (size_t)((K0) + kp) * ID; \
        g0 = *(const float4*)pg_;  g1 = *(const float4*)(pg_ + ID); \
        const float* pu_ = wue + (size_t)((K0) + kp) * ID; \
        u0 = *(const float4*)pu_;  u1 = *(const float4*)(pu_ + ID); \
    } while (0)

#define G1_STORE(B) do { \
        *(v8bf*)&Ald[B][am][aseg * 16]     = cvt8(a0, a1); \
        *(v8bf*)&Ald[B][am][aseg * 16 + 8] = cvt8(a2, a3); \
        float g0a[4] = {g0.x, g0.y, g0.z, g0.w}, g1a[4] = {g1.x, g1.y, g1.z, g1.w}; \
        float u0a[4] = {u0.x, u0.y, u0.z, u0.w}, u1a[4] = {u1.x, u1.y, u1.z, u1.w}; \
        _Pragma("unroll") \
        for (int j = 0; j < 4; j++) { \
            v2bf pg; pg[0] = (__bf16)g0a[j]; pg[1] = (__bf16)g1a[j]; \
            *(v2bf*)&Bg[B][bn + j][bcol] = pg; \
            v2bf pu; pu[0] = (__bf16)u0a[j]; pu[1] = (__bf16)u1a[j]; \
            *(v2bf*)&Bu[B][bn + j][bcol] = pu; \
        } \
    } while (0)

    G1_LOAD(0);
    G1_STORE(0);
    __syncthreads();

    const int NIT = HD / 32;
    for (int it = 0; it < NIT; ++it) {
        int cur = it & 1;
        if (it + 1 < NIT) G1_LOAD((it + 1) * 32);
#pragma unroll
        for (int kh = 0; kh < 2; kh++) {
            int kb = kh * 16 + hh * 8;
            int ho = kh * 2 + hh;
            int bc = 8 * (ho ^ ((ml >> 2) & 3));
            v8bf af0 = *(const v8bf*)&Ald[cur][wm + ml][kb];
            v8bf af1 = *(const v8bf*)&Ald[cur][wm + 32 + ml][kb];
            v8bf bg  = *(const v8bf*)&Bg[cur][wn + ml][bc];
            v8bf bu  = *(const v8bf*)&Bu[cur][wn + ml][bc];
            accg[0] = __builtin_amdgcn_mfma_f32_32x32x16_bf16(af0, bg, accg[0], 0, 0, 0);
            accg[1] = __builtin_amdgcn_mfma_f32_32x32x16_bf16(af1, bg, accg[1], 0, 0, 0);
            accu[0] = __builtin_amdgcn_mfma_f32_32x32x16_bf16(af0, bu, accu[0], 0, 0, 0);
            accu[1] = __builtin_amdgcn_mfma_f32_32x32x16_bf16(af1, bu, accu[1], 0, 0, 0);
        }
        if (it + 1 < NIT) G1_STORE(cur ^ 1);
        __syncthreads();
    }

#pragma unroll
    for (int mt = 0; mt < 2; mt++) {
#pragma unroll
        for (int r = 0; r < 16; r++) {
            int row = wm + mt * 32 + (r & 3) + 8 * (r >> 2) + 4 * hh;
            if (m0 + row < cnt) {
                float g = accg[mt][r];
                float u = accu[mt][r];
                float hv = g / (1.f + __expf(-g)) * u;
                hbuf[(size_t)(base + m0 + row) * ID + n0 + wn + ml] = (__bf16)hv;
            }
        }
    }
}

// ---------------- GEMM2: y = h Wd ----------------
// block tile M128 x N128, double-buffered, register prefetch.
__global__ __launch_bounds__(256) void gemm2_kernel(
    const __bf16* __restrict__ hbuf, const float* __restrict__ wd,
    const int* __restrict__ counts, const int* __restrict__ basev,
    __bf16* __restrict__ ybuf)
{
    int e = blockIdx.z;
    int cnt = counts[e];
    int m0 = blockIdx.y * 128;
    if (m0 >= cnt) return;
    int n0 = blockIdx.x * 128;
    int base = basev[e];

    __shared__ __align__(16) __bf16 Ald[2][128][LDP];
    __shared__ __align__(16) __bf16 Bd[2][128][LDP];

    int tid = threadIdx.x;
    int w = tid >> 6, ln = tid & 63, ml = ln & 31, hh = ln >> 5;
    int wm = (w & 1) * 64, wn = (w >> 1) * 64;

    int am = tid >> 1, aseg = tid & 1;
    int grow = m0 + am;
    int arowi = base + (grow < cnt ? grow : (cnt - 1));
    const __bf16* ap0 = hbuf + (size_t)arowi * ID + aseg * 16;

    int s = tid & 15, P = tid >> 4;
    int bn = s * 4;
    int kp = P * 2;
    int bcol = 8 * ((P >> 2) ^ (s & 3)) + 2 * (P & 3);
    const float* wde = wd + (size_t)e * ID * HD + n0 + bn;

    v16f acc[2][2];
#pragma unroll
    for (int mt = 0; mt < 2; mt++)
#pragma unroll
        for (int nt = 0; nt < 2; nt++)
#pragma unroll
            for (int r = 0; r < 16; r++) acc[mt][nt][r] = 0.f;

    v8bf av0, av1;
    float4 d0[2], d1[2];

#define G2_LOAD(K0) do { \
        av0 = *(const v8bf*)(ap0 + (K0)); \
        av1 = *(const v8bf*)(ap0 + (K0) + 8); \
        _Pragma("unroll") \
        for (int rr = 0; rr < 2; rr++) { \
            const float* pd_ = wde + (size_t)((K0) + kp) * HD + rr * 64; \
            d0[rr] = *(const float4*)pd_; \
            d1[rr] = *(const float4*)(pd_ + HD); \
        } \
    } while (0)

#define G2_STORE(B) do { \
        *(v8bf*)&Ald[B][am][aseg * 16]     = av0; \
        *(v8bf*)&Ald[B][am][aseg * 16 + 8] = av1; \
        _Pragma("unroll") \
        for (int rr = 0; rr < 2; rr++) { \
            float d0a[4] = {d0[rr].x, d0[rr].y, d0[rr].z, d0[rr].w}; \
            float d1a[4] = {d1[rr].x, d1[rr].y, d1[rr].z, d1[rr].w}; \
            _Pragma("unroll") \
            for (int j = 0; j < 4; j++) { \
                v2bf pd; pd[0] = (__bf16)d0a[j]; pd[1] = (__bf16)d1a[j]; \
                *(v2bf*)&Bd[B][bn + j + rr * 64][bcol] = pd; \
            } \
        } \
    } while (0)

    G2_LOAD(0);
    G2_STORE(0);
    __syncthreads();

    const int NIT = ID / 32;
    for (int it = 0; it < NIT; ++it) {
        int cur = it & 1;
        if (it + 1 < NIT) G2_LOAD((it + 1) * 32);
#pragma unroll
        for (int kh = 0; kh < 2; kh++) {
            int kb = kh * 16 + hh * 8;
            int ho = kh * 2 + hh;
            int bc = 8 * (ho ^ ((ml >> 2) & 3));
            v8bf af0 = *(const v8bf*)&Ald[cur][wm + ml][kb];
            v8bf af1 = *(const v8bf*)&Ald[cur][wm + 32 + ml][kb];
            v8bf bf0 = *(const v8bf*)&Bd[cur][wn + ml][bc];
            v8bf bf1 = *(const v8bf*)&Bd[cur][wn + 32 + ml][bc];
            acc[0][0] = __builtin_amdgcn_mfma_f32_32x32x16_bf16(af0, bf0, acc[0][0], 0, 0, 0);
            acc[1][0] = __builtin_amdgcn_mfma_f32_32x32x16_bf16(af1, bf0, acc[1][0], 0, 0, 0);
            acc[0][1] = __builtin_amdgcn_mfma_f32_32x32x16_bf16(af0, bf1, acc[0][1], 0, 0, 0);
            acc[1][1] = __builtin_amdgcn_mfma_f32_32x32x16_bf16(af1, bf1, acc[1][1], 0, 0, 0);
        }
        if (it + 1 < NIT) G2_STORE(cur ^ 1);
        __syncthreads();
    }

#pragma unroll
    for (int mt = 0; mt < 2; mt++) {
#pragma unroll
        for (int nt = 0; nt < 2; nt++) {
#pragma unroll
            for (int r = 0; r < 16; r++) {
                int row = wm + mt * 32 + (r & 3) + 8 * (r >> 2) + 4 * hh;
                if (m0 + row < cnt) {
                    ybuf[(size_t)(base + m0 + row) * HD + n0 + wn + nt * 32 + ml] = (__bf16)acc[mt][nt][r];
                }
            }
        }
    }
}

// ---------------- combine ----------------
__global__ __launch_bounds__(256) void combine_kernel(
    const __bf16* __restrict__ ybuf, const int* __restrict__ toppos, float* __restrict__ out)
{
    int t = blockIdx.x;
    int tid = threadIdx.x;
    int p0 = toppos[t * 2 + 0];
    int p1 = toppos[t * 2 + 1];
    v8bf a = ((const v8bf*)(ybuf + (size_t)p0 * HD))[tid];
    v8bf b = ((const v8bf*)(ybuf + (size_t)p1 * HD))[tid];
    float4 o0, o1;
    o0.x = (float)a[0] + (float)b[0];
    o0.y = (float)a[1] + (float)b[1];
    o0.z = (float)a[2] + (float)b[2];
    o0.w = (float)a[3] + (float)b[3];
    o1.x = (float)a[4] + (float)b[4];
    o1.y = (float)a[5] + (float)b[5];
    o1.z = (float)a[6] + (float)b[6];
    o1.w = (float)a[7] + (float)b[7];
    float* orow = out + (size_t)t * HD + tid * 8;
    *(float4*)orow = o0;
    *(float4*)(orow + 4) = o1;
}

extern "C" void kernel_launch(void* const* d_in, const int* in_sizes, int n_in,
                              void* d_out, int out_size, void* d_ws, size_t ws_size,
                              hipStream_t stream)
{
    const float* x  = (const float*)d_in[0];
    const float* gw = (const float*)d_in[1];
    const float* wg = (const float*)d_in[2];
    const float* wu = (const float*)d_in[3];
    const float* wd = (const float*)d_in[4];
    float* out = (float*)d_out;
    float* logits = out + (size_t)NT * HD;

    char* ws = (char*)d_ws;
    int* counts = (int*)(ws + 0);
    int* base   = (int*)(ws + 64);
    int* cursor = (int*)(ws + 128);
    int* topids = (int*)(ws + 1024);
    int* toppos = (int*)(ws + 1024 + 8192);
    int* rowtok = (int*)(ws + 1024 + 16384);
    __bf16* hbuf = (__bf16*)(ws + 32768);                          // [2048,1024] bf16 = 4 MB
    __bf16* ybuf = (__bf16*)(ws + 32768 + (size_t)2048 * ID * 2);  // [2048,2048] bf16 = 8 MB

    hipMemsetAsync(ws, 0, 256, stream);
    router_kernel<<<NT / 4, 256, 0, stream>>>(x, gw, logits, topids, counts);
    scan_kernel<<<1, 64, 0, stream>>>(counts, base, cursor);
    assign_kernel<<<4, 256, 0, stream>>>(topids, cursor, rowtok, toppos);
    gemm1_kernel<<<dim3(ID / 64, 16, NE), 256, 0, stream>>>(x, wg, wu, counts, base, rowtok, hbuf);
    gemm2_kernel<<<dim3(HD / 128, 16, NE), 256, 0, stream>>>(hbuf, wd, counts, base, ybuf);
    combine_kernel<<<NT, 256, 0, stream>>>(ybuf, toppos, out);
}

// Round 6
// 347.941 us; speedup vs baseline: 1.4988x; 1.0461x over previous
//
#include <hip/hip_runtime.h>
#include <hip/hip_bf16.h>
#include <math.h>

// OLMoE sparse MoE block. fp32 storage, bf16 MFMA compute (32x32x16).
// T=1024, H=2048, I=1024, E=8, top-2, unweighted combine.
// Round 5 (resubmit after broker timeout): tile-table grid compaction
// (kill 87% dead blocks), 2-way B-store swizzle.

#define NT 1024
#define HD 2048
#define ID 1024
#define NE 8
#define LDP 40   // LDS row pitch (bf16 elements)
#define MAXTILES 24

typedef __bf16 v8bf __attribute__((ext_vector_type(8)));
typedef __bf16 v2bf __attribute__((ext_vector_type(2)));
typedef float v16f __attribute__((ext_vector_type(16)));

__device__ __forceinline__ v8bf cvt8(float4 a, float4 b) {
    v8bf v;
    v[0] = (__bf16)a.x; v[1] = (__bf16)a.y; v[2] = (__bf16)a.z; v[3] = (__bf16)a.w;
    v[4] = (__bf16)b.x; v[5] = (__bf16)b.y; v[6] = (__bf16)b.z; v[7] = (__bf16)b.w;
    return v;
}

// ---------------- router: one wave per token ----------------
__global__ __launch_bounds__(256) void router_kernel(
    const float* __restrict__ x, const float* __restrict__ gw,
    float* __restrict__ logits_out, int* __restrict__ topids, int* __restrict__ counts)
{
    int wv = threadIdx.x >> 6, ln = threadIdx.x & 63;
    int t = blockIdx.x * 4 + wv;
    const float* xr = x + (size_t)t * HD + ln * 32;
    float4 xv[8];
#pragma unroll
    for (int i = 0; i < 8; i++) xv[i] = *(const float4*)(xr + i * 4);

    float lg[NE];
#pragma unroll
    for (int e = 0; e < NE; e++) {
        const float* wr = gw + (size_t)e * HD + ln * 32;
        float s = 0.f;
#pragma unroll
        for (int i = 0; i < 8; i++) {
            float4 w4 = *(const float4*)(wr + i * 4);
            s += xv[i].x * w4.x + xv[i].y * w4.y + xv[i].z * w4.z + xv[i].w * w4.w;
        }
#pragma unroll
        for (int off = 32; off > 0; off >>= 1) s += __shfl_down(s, off, 64);
        lg[e] = s;  // valid on lane 0
    }
    if (ln == 0) {
#pragma unroll
        for (int e = 0; e < NE; e++) logits_out[t * NE + e] = lg[e];
        int i1 = 0;
        for (int e = 1; e < NE; e++) if (lg[e] > lg[i1]) i1 = e;
        int i2 = -1;
        for (int e = 0; e < NE; e++) {
            if (e == i1) continue;
            if (i2 < 0 || lg[e] > lg[i2]) i2 = e;
        }
        topids[t * 2 + 0] = i1;
        topids[t * 2 + 1] = i2;
        atomicAdd(&counts[i1], 1);
        atomicAdd(&counts[i2], 1);
    }
}

// ---------------- scan + tile table ----------------
__global__ void scan_kernel(const int* __restrict__ counts, int* __restrict__ base,
                            int* __restrict__ cursor, int* __restrict__ tile_e,
                            int* __restrict__ tile_m)
{
    if (threadIdx.x == 0 && blockIdx.x == 0) {
        int s = 0, nt = 0;
        for (int e = 0; e < NE; e++) {
            base[e] = s; cursor[e] = s;
            for (int m0 = 0; m0 < counts[e]; m0 += 128) {
                tile_e[nt] = e; tile_m[nt] = m0; nt++;
            }
            s += counts[e];
        }
        for (int i = nt; i < MAXTILES; i++) tile_e[i] = -1;
    }
}

__global__ void assign_kernel(const int* __restrict__ topids, int* __restrict__ cursor,
                              int* __restrict__ rowtok, int* __restrict__ toppos)
{
    int t = blockIdx.x * blockDim.x + threadIdx.x;
    if (t < NT) {
#pragma unroll
        for (int s = 0; s < 2; s++) {
            int e = topids[t * 2 + s];
            int pos = atomicAdd(&cursor[e], 1);
            rowtok[pos] = t;
            toppos[t * 2 + s] = pos;
        }
    }
}

// ---------------- GEMM1: h = silu(X Wg) * (X Wu) ----------------
// block tile M128 x N64, tile-table driven, double-buffered LDS.
__global__ __launch_bounds__(256) void gemm1_kernel(
    const float* __restrict__ x, const float* __restrict__ wg, const float* __restrict__ wu,
    const int* __restrict__ counts, const int* __restrict__ basev, const int* __restrict__ rowtok,
    const int* __restrict__ tile_e, const int* __restrict__ tile_m,
    __bf16* __restrict__ hbuf)
{
    int ti = blockIdx.y;
    int e = tile_e[ti];
    if (e < 0) return;
    int m0 = tile_m[ti];
    int cnt = counts[e];
    int n0 = blockIdx.x * 64;
    int base = basev[e];

    __shared__ __align__(16) __bf16 Ald[2][128][LDP];
    __shared__ __align__(16) __bf16 Bg[2][64][LDP];
    __shared__ __align__(16) __bf16 Bu[2][64][LDP];

    int tid = threadIdx.x;
    int w = tid >> 6, ln = tid & 63, ml = ln & 31, hh = ln >> 5;
    int wm = (w & 1) * 64, wn = (w >> 1) * 32;

    int am = tid >> 1, aseg = tid & 1;
    const float* arow = nullptr;
    if (m0 + am < cnt) arow = x + (size_t)rowtok[base + m0 + am] * HD + aseg * 16;

    // B staging: lanes contiguous in n; bank-2-way swizzle f = ho ^ (s&3) ^ (s>>2)
    int s = tid & 15, P = tid >> 4;
    int bn = s * 4;
    int kp = P * 2;
    int bcol = 8 * (((P >> 2) ^ (s & 3)) ^ (s >> 2)) + 2 * (P & 3);
    const float* wge = wg + (size_t)e * HD * ID + n0 + bn;
    const float* wue = wu + (size_t)e * HD * ID + n0 + bn;

    v16f accg[2], accu[2];
#pragma unroll
    for (int mt = 0; mt < 2; mt++)
#pragma unroll
        for (int r = 0; r < 16; r++) { accg[mt][r] = 0.f; accu[mt][r] = 0.f; }

    float4 a0, a1, a2, a3, g0, g1, u0, u1;

#define G1_LOAD(K0) do { \
        if (arow) { \
            a0 = *(const float4*)(arow + (K0)); \
            a1 = *(const float4*)(arow + (K0) + 4); \
            a2 = *(const float4*)(arow + (K0) + 8); \
            a3 = *(const float4*)(arow + (K0) + 12); \
        } else { a0 = a1 = a2 = a3 = (float4){0,0,0,0}; } \
        const float* pg_ = wge + (size_t)((K0) + kp) * ID; \
        g0 = *(const float4*)pg_;  g1 = *(const float4*)(pg_ + ID); \
        const float* pu_ = wue + (size_t)((K0) + kp) * ID; \
        u0 = *(const float4*)pu_;  u1 = *(const float4*)(pu_ + ID); \
    } while (0)

#define G1_STORE(B) do { \
        *(v8bf*)&Ald[B][am][aseg * 16]     = cvt8(a0, a1); \
        *(v8bf*)&Ald[B][am][aseg * 16 + 8] = cvt8(a2, a3); \
        float g0a[4] = {g0.x, g0.y, g0.z, g0.w}, g1a[4] = {g1.x, g1.y, g1.z, g1.w}; \
        float u0a[4] = {u0.x, u0.y, u0.z, u0.w}, u1a[4] = {u1.x, u1.y, u1.z, u1.w}; \
        _Pragma("unroll") \
        for (int j = 0; j < 4; j++) { \
            v2bf pg; pg[0] = (__bf16)g0a[j]; pg[1] = (__bf16)g1a[j]; \
            *(v2bf*)&Bg[B][bn + j][bcol] = pg; \
            v2bf pu; pu[0] = (__bf16)u0a[j]; pu[1] = (__bf16)u1a[j]; \
            *(v2bf*)&Bu[B][bn + j][bcol] = pu; \
        } \
    } while (0)

    G1_LOAD(0);
    G1_STORE(0);
    __syncthreads();

    const int NIT = HD / 32;
    for (int it = 0; it < NIT; ++it) {
        int cur = it & 1;
        if (it + 1 < NIT) G1_LOAD((it + 1) * 32);
#pragma unroll
        for (int kh = 0; kh < 2; kh++) {
            int kb = kh * 16 + hh * 8;
            int ho = kh * 2 + hh;
            int bc = 8 * ((ho ^ ((ml >> 2) & 3)) ^ (((wn + ml) >> 4) & 3));
            v8bf af0 = *(const v8bf*)&Ald[cur][wm + ml][kb];
            v8bf af1 = *(const v8bf*)&Ald[cur][wm + 32 + ml][kb];
            v8bf bg  = *(const v8bf*)&Bg[cur][wn + ml][bc];
            v8bf bu  = *(const v8bf*)&Bu[cur][wn + ml][bc];
            accg[0] = __builtin_amdgcn_mfma_f32_32x32x16_bf16(af0, bg, accg[0], 0, 0, 0);
            accg[1] = __builtin_amdgcn_mfma_f32_32x32x16_bf16(af1, bg, accg[1], 0, 0, 0);
            accu[0] = __builtin_amdgcn_mfma_f32_32x32x16_bf16(af0, bu, accu[0], 0, 0, 0);
            accu[1] = __builtin_amdgcn_mfma_f32_32x32x16_bf16(af1, bu, accu[1], 0, 0, 0);
        }
        if (it + 1 < NIT) G1_STORE(cur ^ 1);
        __syncthreads();
    }

#pragma unroll
    for (int mt = 0; mt < 2; mt++) {
#pragma unroll
        for (int r = 0; r < 16; r++) {
            int row = wm + mt * 32 + (r & 3) + 8 * (r >> 2) + 4 * hh;
            if (m0 + row < cnt) {
                float g = accg[mt][r];
                float u = accu[mt][r];
                float hv = g / (1.f + __expf(-g)) * u;
                hbuf[(size_t)(base + m0 + row) * ID + n0 + wn + ml] = (__bf16)hv;
            }
        }
    }
}

// ---------------- GEMM2: y = h Wd ----------------
// block tile M128 x N128, tile-table driven, double-buffered.
__global__ __launch_bounds__(256) void gemm2_kernel(
    const __bf16* __restrict__ hbuf, const float* __restrict__ wd,
    const int* __restrict__ counts, const int* __restrict__ basev,
    const int* __restrict__ tile_e, const int* __restrict__ tile_m,
    __bf16* __restrict__ ybuf)
{
    int ti = blockIdx.y;
    int e = tile_e[ti];
    if (e < 0) return;
    int m0 = tile_m[ti];
    int cnt = counts[e];
    int n0 = blockIdx.x * 128;
    int base = basev[e];

    __shared__ __align__(16) __bf16 Ald[2][128][LDP];
    __shared__ __align__(16) __bf16 Bd[2][128][LDP];

    int tid = threadIdx.x;
    int w = tid >> 6, ln = tid & 63, ml = ln & 31, hh = ln >> 5;
    int wm = (w & 1) * 64, wn = (w >> 1) * 64;

    int am = tid >> 1, aseg = tid & 1;
    int grow = m0 + am;
    int arowi = base + (grow < cnt ? grow : (cnt - 1));
    const __bf16* ap0 = hbuf + (size_t)arowi * ID + aseg * 16;

    int s = tid & 15, P = tid >> 4;
    int bn = s * 4;
    int kp = P * 2;
    int bcol = 8 * (((P >> 2) ^ (s & 3)) ^ (s >> 2)) + 2 * (P & 3);
    const float* wde = wd + (size_t)e * ID * HD + n0 + bn;

    v16f acc[2][2];
#pragma unroll
    for (int mt = 0; mt < 2; mt++)
#pragma unroll
        for (int nt = 0; nt < 2; nt++)
#pragma unroll
            for (int r = 0; r < 16; r++) acc[mt][nt][r] = 0.f;

    v8bf av0, av1;
    float4 d0[2], d1[2];

#define G2_LOAD(K0) do { \
        av0 = *(const v8bf*)(ap0 + (K0)); \
        av1 = *(const v8bf*)(ap0 + (K0) + 8); \
        _Pragma("unroll") \
        for (int rr = 0; rr < 2; rr++) { \
            const float* pd_ = wde + (size_t)((K0) + kp) * HD + rr * 64; \
            d0[rr] = *(const float4*)pd_; \
            d1[rr] = *(const float4*)(pd_ + HD); \
        } \
    } while (0)

#define G2_STORE(B) do { \
        *(v8bf*)&Ald[B][am][aseg * 16]     = av0; \
        *(v8bf*)&Ald[B][am][aseg * 16 + 8] = av1; \
        _Pragma("unroll") \
        for (int rr = 0; rr < 2; rr++) { \
            float d0a[4] = {d0[rr].x, d0[rr].y, d0[rr].z, d0[rr].w}; \
            float d1a[4] = {d1[rr].x, d1[rr].y, d1[rr].z, d1[rr].w}; \
            _Pragma("unroll") \
            for (int j = 0; j < 4; j++) { \
                v2bf pd; pd[0] = (__bf16)d0a[j]; pd[1] = (__bf16)d1a[j]; \
                *(v2bf*)&Bd[B][bn + j + rr * 64][bcol] = pd; \
            } \
        } \
    } while (0)

    G2_LOAD(0);
    G2_STORE(0);
    __syncthreads();

    const int NIT = ID / 32;
    for (int it = 0; it < NIT; ++it) {
        int cur = it & 1;
        if (it + 1 < NIT) G2_LOAD((it + 1) * 32);
#pragma unroll
        for (int kh = 0; kh < 2; kh++) {
            int kb = kh * 16 + hh * 8;
            int ho = kh * 2 + hh;
            int f0 = (ho ^ ((ml >> 2) & 3)) ^ (((wn + ml) >> 4) & 3);
            int bc0 = 8 * f0;
            int bc1 = 8 * (f0 ^ 2);  // rows wn+32+ml: (n>>4)&3 differs by 2
            v8bf af0 = *(const v8bf*)&Ald[cur][wm + ml][kb];
            v8bf af1 = *(const v8bf*)&Ald[cur][wm + 32 + ml][kb];
            v8bf bf0 = *(const v8bf*)&Bd[cur][wn + ml][bc0];
            v8bf bf1 = *(const v8bf*)&Bd[cur][wn + 32 + ml][bc1];
            acc[0][0] = __builtin_amdgcn_mfma_f32_32x32x16_bf16(af0, bf0, acc[0][0], 0, 0, 0);
            acc[1][0] = __builtin_amdgcn_mfma_f32_32x32x16_bf16(af1, bf0, acc[1][0], 0, 0, 0);
            acc[0][1] = __builtin_amdgcn_mfma_f32_32x32x16_bf16(af0, bf1, acc[0][1], 0, 0, 0);
            acc[1][1] = __builtin_amdgcn_mfma_f32_32x32x16_bf16(af1, bf1, acc[1][1], 0, 0, 0);
        }
        if (it + 1 < NIT) G2_STORE(cur ^ 1);
        __syncthreads();
    }

#pragma unroll
    for (int mt = 0; mt < 2; mt++) {
#pragma unroll
        for (int nt = 0; nt < 2; nt++) {
#pragma unroll
            for (int r = 0; r < 16; r++) {
                int row = wm + mt * 32 + (r & 3) + 8 * (r >> 2) + 4 * hh;
                if (m0 + row < cnt) {
                    ybuf[(size_t)(base + m0 + row) * HD + n0 + wn + nt * 32 + ml] = (__bf16)acc[mt][nt][r];
                }
            }
        }
    }
}

// ---------------- combine ----------------
__global__ __launch_bounds__(256) void combine_kernel(
    const __bf16* __restrict__ ybuf, const int* __restrict__ toppos, float* __restrict__ out)
{
    int t = blockIdx.x;
    int tid = threadIdx.x;
    int p0 = toppos[t * 2 + 0];
    int p1 = toppos[t * 2 + 1];
    v8bf a = ((const v8bf*)(ybuf + (size_t)p0 * HD))[tid];
    v8bf b = ((const v8bf*)(ybuf + (size_t)p1 * HD))[tid];
    float4 o0, o1;
    o0.x = (float)a[0] + (float)b[0];
    o0.y = (float)a[1] + (float)b[1];
    o0.z = (float)a[2] + (float)b[2];
    o0.w = (float)a[3] + (float)b[3];
    o1.x = (float)a[4] + (float)b[4];
    o1.y = (float)a[5] + (float)b[5];
    o1.z = (float)a[6] + (float)b[6];
    o1.w = (float)a[7] + (float)b[7];
    float* orow = out + (size_t)t * HD + tid * 8;
    *(float4*)orow = o0;
    *(float4*)(orow + 4) = o1;
}

extern "C" void kernel_launch(void* const* d_in, const int* in_sizes, int n_in,
                              void* d_out, int out_size, void* d_ws, size_t ws_size,
                              hipStream_t stream)
{
    const float* x  = (const float*)d_in[0];
    const float* gw = (const float*)d_in[1];
    const float* wg = (const float*)d_in[2];
    const float* wu = (const float*)d_in[3];
    const float* wd = (const float*)d_in[4];
    float* out = (float*)d_out;
    float* logits = out + (size_t)NT * HD;

    char* ws = (char*)d_ws;
    int* counts = (int*)(ws + 0);
    int* base   = (int*)(ws + 64);
    int* cursor = (int*)(ws + 128);
    int* tile_e = (int*)(ws + 256);   // MAXTILES ints
    int* tile_m = (int*)(ws + 384);   // MAXTILES ints
    int* topids = (int*)(ws + 1024);
    int* toppos = (int*)(ws + 1024 + 8192);
    int* rowtok = (int*)(ws + 1024 + 16384);
    __bf16* hbuf = (__bf16*)(ws + 32768);                          // [2048,1024] bf16 = 4 MB
    __bf16* ybuf = (__bf16*)(ws + 32768 + (size_t)2048 * ID * 2);  // [2048,2048] bf16 = 8 MB

    hipMemsetAsync(ws, 0, 256, stream);
    router_kernel<<<NT / 4, 256, 0, stream>>>(x, gw, logits, topids, counts);
    scan_kernel<<<1, 64, 0, stream>>>(counts, base, cursor, tile_e, tile_m);
    assign_kernel<<<4, 256, 0, stream>>>(topids, cursor, rowtok, toppos);
    gemm1_kernel<<<dim3(ID / 64, MAXTILES), 256, 0, stream>>>(x, wg, wu, counts, base, rowtok, tile_e, tile_m, hbuf);
    gemm2_kernel<<<dim3(HD / 128, MAXTILES), 256, 0, stream>>>(hbuf, wd, counts, base, tile_e, tile_m, ybuf);
    combine_kernel<<<NT, 256, 0, stream>>>(ybuf, toppos, out);
}

// Round 7
// 321.699 us; speedup vs baseline: 1.6210x; 1.0816x over previous
//
#include <hip/hip_runtime.h>
#include <hip/hip_bf16.h>
#include <math.h>

// OLMoE sparse MoE block. fp32 storage, bf16 MFMA compute (32x32x16).
// T=1024, H=2048, I=1024, E=8, top-2, unweighted combine.
// Round 7: distance-2 register prefetch (loads stay 2 iterations ahead;
// LDS stores wait vmcnt(8) not vmcnt(0)) on both GEMMs.

#define NT 1024
#define HD 2048
#define ID 1024
#define NE 8
#define LDP 40   // LDS row pitch (bf16 elements)
#define MAXTILES 24

typedef __bf16 v8bf __attribute__((ext_vector_type(8)));
typedef __bf16 v2bf __attribute__((ext_vector_type(2)));
typedef float v16f __attribute__((ext_vector_type(16)));

__device__ __forceinline__ v8bf cvt8(float4 a, float4 b) {
    v8bf v;
    v[0] = (__bf16)a.x; v[1] = (__bf16)a.y; v[2] = (__bf16)a.z; v[3] = (__bf16)a.w;
    v[4] = (__bf16)b.x; v[5] = (__bf16)b.y; v[6] = (__bf16)b.z; v[7] = (__bf16)b.w;
    return v;
}

// ---------------- router: one wave per token ----------------
__global__ __launch_bounds__(256) void router_kernel(
    const float* __restrict__ x, const float* __restrict__ gw,
    float* __restrict__ logits_out, int* __restrict__ topids, int* __restrict__ counts)
{
    int wv = threadIdx.x >> 6, ln = threadIdx.x & 63;
    int t = blockIdx.x * 4 + wv;
    const float* xr = x + (size_t)t * HD + ln * 32;
    float4 xv[8];
#pragma unroll
    for (int i = 0; i < 8; i++) xv[i] = *(const float4*)(xr + i * 4);

    float lg[NE];
#pragma unroll
    for (int e = 0; e < NE; e++) {
        const float* wr = gw + (size_t)e * HD + ln * 32;
        float s = 0.f;
#pragma unroll
        for (int i = 0; i < 8; i++) {
            float4 w4 = *(const float4*)(wr + i * 4);
            s += xv[i].x * w4.x + xv[i].y * w4.y + xv[i].z * w4.z + xv[i].w * w4.w;
        }
#pragma unroll
        for (int off = 32; off > 0; off >>= 1) s += __shfl_down(s, off, 64);
        lg[e] = s;  // valid on lane 0
    }
    if (ln == 0) {
#pragma unroll
        for (int e = 0; e < NE; e++) logits_out[t * NE + e] = lg[e];
        int i1 = 0;
        for (int e = 1; e < NE; e++) if (lg[e] > lg[i1]) i1 = e;
        int i2 = -1;
        for (int e = 0; e < NE; e++) {
            if (e == i1) continue;
            if (i2 < 0 || lg[e] > lg[i2]) i2 = e;
        }
        topids[t * 2 + 0] = i1;
        topids[t * 2 + 1] = i2;
        atomicAdd(&counts[i1], 1);
        atomicAdd(&counts[i2], 1);
    }
}

// ---------------- scan + tile table ----------------
__global__ void scan_kernel(const int* __restrict__ counts, int* __restrict__ base,
                            int* __restrict__ cursor, int* __restrict__ tile_e,
                            int* __restrict__ tile_m)
{
    if (threadIdx.x == 0 && blockIdx.x == 0) {
        int s = 0, nt = 0;
        for (int e = 0; e < NE; e++) {
            base[e] = s; cursor[e] = s;
            for (int m0 = 0; m0 < counts[e]; m0 += 128) {
                tile_e[nt] = e; tile_m[nt] = m0; nt++;
            }
            s += counts[e];
        }
        for (int i = nt; i < MAXTILES; i++) tile_e[i] = -1;
    }
}

__global__ void assign_kernel(const int* __restrict__ topids, int* __restrict__ cursor,
                              int* __restrict__ rowtok, int* __restrict__ toppos)
{
    int t = blockIdx.x * blockDim.x + threadIdx.x;
    if (t < NT) {
#pragma unroll
        for (int s = 0; s < 2; s++) {
            int e = topids[t * 2 + s];
            int pos = atomicAdd(&cursor[e], 1);
            rowtok[pos] = t;
            toppos[t * 2 + s] = pos;
        }
    }
}

// ---------------- GEMM1: h = silu(X Wg) * (X Wu) ----------------
// block tile M128 x N64, tile-table driven, dbuf LDS + distance-2 reg prefetch.
struct G1R { float4 a0, a1, a2, a3, g0, g1, u0, u1; };

__global__ __launch_bounds__(256) void gemm1_kernel(
    const float* __restrict__ x, const float* __restrict__ wg, const float* __restrict__ wu,
    const int* __restrict__ counts, const int* __restrict__ basev, const int* __restrict__ rowtok,
    const int* __restrict__ tile_e, const int* __restrict__ tile_m,
    __bf16* __restrict__ hbuf)
{
    int ti = blockIdx.y;
    int e = tile_e[ti];
    if (e < 0) return;
    int m0 = tile_m[ti];
    int cnt = counts[e];
    int n0 = blockIdx.x * 64;
    int base = basev[e];

    __shared__ __align__(16) __bf16 Ald[2][128][LDP];
    __shared__ __align__(16) __bf16 Bg[2][64][LDP];
    __shared__ __align__(16) __bf16 Bu[2][64][LDP];

    int tid = threadIdx.x;
    int w = tid >> 6, ln = tid & 63, ml = ln & 31, hh = ln >> 5;
    int wm = (w & 1) * 64, wn = (w >> 1) * 32;

    int am = tid >> 1, aseg = tid & 1;
    const float* arow = nullptr;
    if (m0 + am < cnt) arow = x + (size_t)rowtok[base + m0 + am] * HD + aseg * 16;

    int s = tid & 15, P = tid >> 4;
    int bn = s * 4;
    int kp = P * 2;
    int bcol = 8 * (((P >> 2) ^ (s & 3)) ^ (s >> 2)) + 2 * (P & 3);
    const float* wge = wg + (size_t)e * HD * ID + n0 + bn;
    const float* wue = wu + (size_t)e * HD * ID + n0 + bn;

    v16f accg[2], accu[2];
#pragma unroll
    for (int mt = 0; mt < 2; mt++)
#pragma unroll
        for (int r = 0; r < 16; r++) { accg[mt][r] = 0.f; accu[mt][r] = 0.f; }

    auto g1_load = [&](G1R& r, int K0) {
        if (arow) {
            r.a0 = *(const float4*)(arow + K0);
            r.a1 = *(const float4*)(arow + K0 + 4);
            r.a2 = *(const float4*)(arow + K0 + 8);
            r.a3 = *(const float4*)(arow + K0 + 12);
        } else { r.a0 = r.a1 = r.a2 = r.a3 = (float4){0,0,0,0}; }
        const float* pg_ = wge + (size_t)(K0 + kp) * ID;
        r.g0 = *(const float4*)pg_;  r.g1 = *(const float4*)(pg_ + ID);
        const float* pu_ = wue + (size_t)(K0 + kp) * ID;
        r.u0 = *(const float4*)pu_;  r.u1 = *(const float4*)(pu_ + ID);
    };

    auto g1_store = [&](const G1R& r, int B) {
        *(v8bf*)&Ald[B][am][aseg * 16]     = cvt8(r.a0, r.a1);
        *(v8bf*)&Ald[B][am][aseg * 16 + 8] = cvt8(r.a2, r.a3);
        float g0a[4] = {r.g0.x, r.g0.y, r.g0.z, r.g0.w}, g1a[4] = {r.g1.x, r.g1.y, r.g1.z, r.g1.w};
        float u0a[4] = {r.u0.x, r.u0.y, r.u0.z, r.u0.w}, u1a[4] = {r.u1.x, r.u1.y, r.u1.z, r.u1.w};
#pragma unroll
        for (int j = 0; j < 4; j++) {
            v2bf pg; pg[0] = (__bf16)g0a[j]; pg[1] = (__bf16)g1a[j];
            *(v2bf*)&Bg[B][bn + j][bcol] = pg;
            v2bf pu; pu[0] = (__bf16)u0a[j]; pu[1] = (__bf16)u1a[j];
            *(v2bf*)&Bu[B][bn + j][bcol] = pu;
        }
    };

    auto g1_mfma = [&](int B) {
#pragma unroll
        for (int kh = 0; kh < 2; kh++) {
            int kb = kh * 16 + hh * 8;
            int ho = kh * 2 + hh;
            int bc = 8 * ((ho ^ ((ml >> 2) & 3)) ^ (((wn + ml) >> 4) & 3));
            v8bf af0 = *(const v8bf*)&Ald[B][wm + ml][kb];
            v8bf af1 = *(const v8bf*)&Ald[B][wm + 32 + ml][kb];
            v8bf bg  = *(const v8bf*)&Bg[B][wn + ml][bc];
            v8bf bu  = *(const v8bf*)&Bu[B][wn + ml][bc];
            accg[0] = __builtin_amdgcn_mfma_f32_32x32x16_bf16(af0, bg, accg[0], 0, 0, 0);
            accg[1] = __builtin_amdgcn_mfma_f32_32x32x16_bf16(af1, bg, accg[1], 0, 0, 0);
            accu[0] = __builtin_amdgcn_mfma_f32_32x32x16_bf16(af0, bu, accu[0], 0, 0, 0);
            accu[1] = __builtin_amdgcn_mfma_f32_32x32x16_bf16(af1, bu, accu[1], 0, 0, 0);
        }
    };

    const int NIT = HD / 32;  // 64, even
    G1R r0, r1;
    g1_load(r0, 0);
    g1_load(r1, 32);
    g1_store(r0, 0);
    __syncthreads();

    for (int it = 0; it < NIT; it += 2) {
        if (it + 2 < NIT) g1_load(r0, (it + 2) * 32);
        g1_mfma(0);
        if (it + 1 < NIT) g1_store(r1, 1);
        __syncthreads();
        if (it + 3 < NIT) g1_load(r1, (it + 3) * 32);
        g1_mfma(1);
        if (it + 2 < NIT) g1_store(r0, 0);
        __syncthreads();
    }

#pragma unroll
    for (int mt = 0; mt < 2; mt++) {
#pragma unroll
        for (int r = 0; r < 16; r++) {
            int row = wm + mt * 32 + (r & 3) + 8 * (r >> 2) + 4 * hh;
            if (m0 + row < cnt) {
                float g = accg[mt][r];
                float u = accu[mt][r];
                float hv = g / (1.f + __expf(-g)) * u;
                hbuf[(size_t)(base + m0 + row) * ID + n0 + wn + ml] = (__bf16)hv;
            }
        }
    }
}

// ---------------- GEMM2: y = h Wd ----------------
// block tile M128 x N128, tile-table driven, dbuf LDS + distance-2 reg prefetch.
struct G2R { v8bf av0, av1; float4 d00, d01, d10, d11; };

__global__ __launch_bounds__(256) void gemm2_kernel(
    const __bf16* __restrict__ hbuf, const float* __restrict__ wd,
    const int* __restrict__ counts, const int* __restrict__ basev,
    const int* __restrict__ tile_e, const int* __restrict__ tile_m,
    __bf16* __restrict__ ybuf)
{
    int ti = blockIdx.y;
    int e = tile_e[ti];
    if (e < 0) return;
    int m0 = tile_m[ti];
    int cnt = counts[e];
    int n0 = blockIdx.x * 128;
    int base = basev[e];

    __shared__ __align__(16) __bf16 Ald[2][128][LDP];
    __shared__ __align__(16) __bf16 Bd[2][128][LDP];

    int tid = threadIdx.x;
    int w = tid >> 6, ln = tid & 63, ml = ln & 31, hh = ln >> 5;
    int wm = (w & 1) * 64, wn = (w >> 1) * 64;

    int am = tid >> 1, aseg = tid & 1;
    int grow = m0 + am;
    int arowi = base + (grow < cnt ? grow : (cnt - 1));
    const __bf16* ap0 = hbuf + (size_t)arowi * ID + aseg * 16;

    int s = tid & 15, P = tid >> 4;
    int bn = s * 4;
    int kp = P * 2;
    int bcol = 8 * (((P >> 2) ^ (s & 3)) ^ (s >> 2)) + 2 * (P & 3);
    const float* wde = wd + (size_t)e * ID * HD + n0 + bn;

    v16f acc[2][2];
#pragma unroll
    for (int mt = 0; mt < 2; mt++)
#pragma unroll
        for (int nt = 0; nt < 2; nt++)
#pragma unroll
            for (int r = 0; r < 16; r++) acc[mt][nt][r] = 0.f;

    auto g2_load = [&](G2R& r, int K0) {
        r.av0 = *(const v8bf*)(ap0 + K0);
        r.av1 = *(const v8bf*)(ap0 + K0 + 8);
        const float* p0 = wde + (size_t)(K0 + kp) * HD;
        r.d00 = *(const float4*)p0;
        r.d10 = *(const float4*)(p0 + HD);
        r.d01 = *(const float4*)(p0 + 64);
        r.d11 = *(const float4*)(p0 + HD + 64);
    };

    auto g2_store = [&](const G2R& r, int B) {
        *(v8bf*)&Ald[B][am][aseg * 16]     = r.av0;
        *(v8bf*)&Ald[B][am][aseg * 16 + 8] = r.av1;
        float d0a[4] = {r.d00.x, r.d00.y, r.d00.z, r.d00.w};
        float d1a[4] = {r.d10.x, r.d10.y, r.d10.z, r.d10.w};
        float e0a[4] = {r.d01.x, r.d01.y, r.d01.z, r.d01.w};
        float e1a[4] = {r.d11.x, r.d11.y, r.d11.z, r.d11.w};
#pragma unroll
        for (int j = 0; j < 4; j++) {
            v2bf pd; pd[0] = (__bf16)d0a[j]; pd[1] = (__bf16)d1a[j];
            *(v2bf*)&Bd[B][bn + j][bcol] = pd;
            v2bf pe; pe[0] = (__bf16)e0a[j]; pe[1] = (__bf16)e1a[j];
            *(v2bf*)&Bd[B][bn + j + 64][bcol] = pe;
        }
    };

    auto g2_mfma = [&](int B) {
#pragma unroll
        for (int kh = 0; kh < 2; kh++) {
            int kb = kh * 16 + hh * 8;
            int ho = kh * 2 + hh;
            int f0 = (ho ^ ((ml >> 2) & 3)) ^ (((wn + ml) >> 4) & 3);
            int bc0 = 8 * f0;
            int bc1 = 8 * (f0 ^ 2);  // rows wn+32+ml: (n>>4)&3 differs by 2
            v8bf af0 = *(const v8bf*)&Ald[B][wm + ml][kb];
            v8bf af1 = *(const v8bf*)&Ald[B][wm + 32 + ml][kb];
            v8bf bf0 = *(const v8bf*)&Bd[B][wn + ml][bc0];
            v8bf bf1 = *(const v8bf*)&Bd[B][wn + 32 + ml][bc1];
            acc[0][0] = __builtin_amdgcn_mfma_f32_32x32x16_bf16(af0, bf0, acc[0][0], 0, 0, 0);
            acc[1][0] = __builtin_amdgcn_mfma_f32_32x32x16_bf16(af1, bf0, acc[1][0], 0, 0, 0);
            acc[0][1] = __builtin_amdgcn_mfma_f32_32x32x16_bf16(af0, bf1, acc[0][1], 0, 0, 0);
            acc[1][1] = __builtin_amdgcn_mfma_f32_32x32x16_bf16(af1, bf1, acc[1][1], 0, 0, 0);
        }
    };

    const int NIT = ID / 32;  // 32, even
    G2R r0, r1;
    g2_load(r0, 0);
    g2_load(r1, 32);
    g2_store(r0, 0);
    __syncthreads();

    for (int it = 0; it < NIT; it += 2) {
        if (it + 2 < NIT) g2_load(r0, (it + 2) * 32);
        g2_mfma(0);
        if (it + 1 < NIT) g2_store(r1, 1);
        __syncthreads();
        if (it + 3 < NIT) g2_load(r1, (it + 3) * 32);
        g2_mfma(1);
        if (it + 2 < NIT) g2_store(r0, 0);
        __syncthreads();
    }

#pragma unroll
    for (int mt = 0; mt < 2; mt++) {
#pragma unroll
        for (int nt = 0; nt < 2; nt++) {
#pragma unroll
            for (int r = 0; r < 16; r++) {
                int row = wm + mt * 32 + (r & 3) + 8 * (r >> 2) + 4 * hh;
                if (m0 + row < cnt) {
                    ybuf[(size_t)(base + m0 + row) * HD + n0 + wn + nt * 32 + ml] = (__bf16)acc[mt][nt][r];
                }
            }
        }
    }
}

// ---------------- combine ----------------
__global__ __launch_bounds__(256) void combine_kernel(
    const __bf16* __restrict__ ybuf, const int* __restrict__ toppos, float* __restrict__ out)
{
    int t = blockIdx.x;
    int tid = threadIdx.x;
    int p0 = toppos[t * 2 + 0];
    int p1 = toppos[t * 2 + 1];
    v8bf a = ((const v8bf*)(ybuf + (size_t)p0 * HD))[tid];
    v8bf b = ((const v8bf*)(ybuf + (size_t)p1 * HD))[tid];
    float4 o0, o1;
    o0.x = (float)a[0] + (float)b[0];
    o0.y = (float)a[1] + (float)b[1];
    o0.z = (float)a[2] + (float)b[2];
    o0.w = (float)a[3] + (float)b[3];
    o1.x = (float)a[4] + (float)b[4];
    o1.y = (float)a[5] + (float)b[5];
    o1.z = (float)a[6] + (float)b[6];
    o1.w = (float)a[7] + (float)b[7];
    float* orow = out + (size_t)t * HD + tid * 8;
    *(float4*)orow = o0;
    *(float4*)(orow + 4) = o1;
}

extern "C" void kernel_launch(void* const* d_in, const int* in_sizes, int n_in,
                              void* d_out, int out_size, void* d_ws, size_t ws_size,
                              hipStream_t stream)
{
    const float* x  = (const float*)d_in[0];
    const float* gw = (const float*)d_in[1];
    const float* wg = (const float*)d_in[2];
    const float* wu = (const float*)d_in[3];
    const float* wd = (const float*)d_in[4];
    float* out = (float*)d_out;
    float* logits = out + (size_t)NT * HD;

    char* ws = (char*)d_ws;
    int* counts = (int*)(ws + 0);
    int* base   = (int*)(ws + 64);
    int* cursor = (int*)(ws + 128);
    int* tile_e = (int*)(ws + 256);   // MAXTILES ints
    int* tile_m = (int*)(ws + 384);   // MAXTILES ints
    int* topids = (int*)(ws + 1024);
    int* toppos = (int*)(ws + 1024 + 8192);
    int* rowtok = (int*)(ws + 1024 + 16384);
    __bf16* hbuf = (__bf16*)(ws + 32768);                          // [2048,1024] bf16 = 4 MB
    __bf16* ybuf = (__bf16*)(ws + 32768 + (size_t)2048 * ID * 2);  // [2048,2048] bf16 = 8 MB

    hipMemsetAsync(ws, 0, 256, stream);
    router_kernel<<<NT / 4, 256, 0, stream>>>(x, gw, logits, topids, counts);
    scan_kernel<<<1, 64, 0, stream>>>(counts, base, cursor, tile_e, tile_m);
    assign_kernel<<<4, 256, 0, stream>>>(topids, cursor, rowtok, toppos);
    gemm1_kernel<<<dim3(ID / 64, MAXTILES), 256, 0, stream>>>(x, wg, wu, counts, base, rowtok, tile_e, tile_m, hbuf);
    gemm2_kernel<<<dim3(HD / 128, MAXTILES), 256, 0, stream>>>(hbuf, wd, counts, base, tile_e, tile_m, ybuf);
    combine_kernel<<<NT, 256, 0, stream>>>(ybuf, toppos, out);
}